// Round 12
// baseline (85.219 us; speedup 1.0000x reference)
//
#include <hip/hip_runtime.h>

#define M_HALF 16384
#define D 128
#define C 64
#define NBLK 256
#define NTHR 256
#define K3_ROWS 64

// Single fused kernel; grid-wide sync via arrive-and-spin barrier.
// Counter is zeroed each call by an in-graph hipMemsetAsync (4 bytes).
__global__ __launch_bounds__(NTHR) void fused_proto_loss(
    const float* __restrict__ x, const int* __restrict__ y,
    float* __restrict__ partials,   // [NBLK][4][C][32]  (kq, c, j)
    float* __restrict__ pTg,        // 8192 floats, finalized pT table
    int*   __restrict__ syncCnt,    // 1 int, memset to 0 before kernel
    float* __restrict__ out)
{
    __shared__ float4 pT4[32 * 64];     // 32 KB (phase C)
    __shared__ float  red[8][33];       // phase B
    __shared__ int    cred[4];
    __shared__ float  wsum[4];

    const int tid  = threadIdx.x;
    const int lane = tid & 63;
    const int blk  = blockIdx.x;

    // ---------------- Phase A: ballot-gather partials (r10 K1, verbatim) ----
    {
        const int kq   = tid >> 6;               // wave id = k-quarter
        const int base = blk * 64;
        const int ycl  = y[base + lane];         // class of row 'lane'
        unsigned long long mymask = 0ULL;
        for (int ci = 0; ci < C; ++ci) {
            const unsigned long long m = __ballot(ycl == ci);
            if (lane == ci) mymask = m;
        }
        float acc[32];
        #pragma unroll
        for (int j = 0; j < 32; ++j) acc[j] = 0.f;
        unsigned long long m = mymask;
        while (m) {
            const int r = (int)__builtin_ctzll(m);
            m &= m - 1;
            const float4* xr = (const float4*)(x + (size_t)(base + r) * D + kq * 32);
            #pragma unroll
            for (int j4 = 0; j4 < 8; ++j4) {
                const float4 v = xr[j4];
                acc[j4*4+0] += v.x; acc[j4*4+1] += v.y;
                acc[j4*4+2] += v.z; acc[j4*4+3] += v.w;
            }
        }
        float* outp = partials + (size_t)blk * (C * D) + (kq * 64 + lane) * 32;
        #pragma unroll
        for (int j4 = 0; j4 < 8; ++j4)
            *(float4*)&outp[j4 * 4] =
                make_float4(acc[j4*4], acc[j4*4+1], acc[j4*4+2], acc[j4*4+3]);
        if (blk == 0 && tid == 0) out[0] = 0.f;  // before any phase-C atomicAdd
    }

    // ---------------- grid sync #1 (all partials visible) --------------------
    __syncthreads();
    if (tid == 0) {
        __threadfence();                         // release
        atomicAdd(syncCnt, 1);
        int guard = 0;
        while (atomicAdd(syncCnt, 0) < NBLK && guard < (1 << 26)) {
            __builtin_amdgcn_s_sleep(2); ++guard;
        }
        __threadfence();                         // acquire
    }
    __syncthreads();

    // ---------------- Phase B: reduce 32 slots + self-count (r11 K2) --------
    {
        const int myc = blk & 63;                // this block's class
        int cnt = 0;
        const int4* y4 = (const int4*)y;
        #pragma unroll 4
        for (int i = tid; i < M_HALF / 4; i += NTHR) {
            const int4 v = y4[i];
            cnt += (v.x == myc) + (v.y == myc) + (v.z == myc) + (v.w == myc);
        }
        #pragma unroll
        for (int off = 32; off; off >>= 1) cnt += __shfl_xor(cnt, off);
        if ((tid & 63) == 0) cred[tid >> 6] = cnt;

        const int sub  = tid >> 5;
        const int pidx = tid & 31;
        const int q    = blk * 32 + pidx;        // flat [kq][c][j]
        float s = 0.f;
        const int b0 = sub * 32;
        #pragma unroll 8
        for (int i = 0; i < 32; ++i)
            s += partials[(size_t)(b0 + i) * (C * D) + q];   // 128B coalesced
        red[sub][pidx] = s;
        __syncthreads();

        if (tid < 32) {
            float tot = 0.f;
            #pragma unroll
            for (int u = 0; u < 8; ++u) tot += red[u][tid];
            float c = (float)(cred[0] + cred[1] + cred[2] + cred[3]);
            if (c < 0.5f) c = 1.f;               // class_counts + (counts < 0.01)
            tot /= c;
            const int k = (blk >> 6) * 32 + tid; // kq*32 + j
            pTg[((k >> 2) * 64 + (myc & 3) * 16 + (myc >> 2)) * 4 + (k & 3)] = tot;
        }
    }

    // ---------------- grid sync #2 (pTg complete) ----------------------------
    __syncthreads();
    if (tid == 0) {
        __threadfence();
        atomicAdd(syncCnt, 1);
        int guard = 0;
        while (atomicAdd(syncCnt, 0) < 2 * NBLK && guard < (1 << 26)) {
            __builtin_amdgcn_s_sleep(2); ++guard;
        }
        __threadfence();
    }
    __syncthreads();

    // ---------------- Phase C: distances + logsumexp + loss (r11 K3) --------
    {
        const float4* pTg4 = (const float4*)pTg;
        for (int o = tid; o < 32 * 64; o += NTHR) pT4[o] = pTg4[o];
        __syncthreads();

        const int wid  = tid >> 6;
        const int cg   = lane & 15;      // classes 4*cg + cc
        const int rg   = lane >> 4;      // row group within wave
        const int rbase = wid * 16 + rg * 4;   // wave: 16 rows; thread: 4 rows
        const int row0 = M_HALF + blk * K3_ROWS;

        const float4* xrow[4];
        #pragma unroll
        for (int r = 0; r < 4; ++r)
            xrow[r] = (const float4*)(x + (size_t)(row0 + rbase + r) * D);

        float acc[4][4];
        #pragma unroll
        for (int r = 0; r < 4; ++r)
            #pragma unroll
            for (int cc = 0; cc < 4; ++cc) acc[r][cc] = 0.f;

        #pragma unroll 2
        for (int k4 = 0; k4 < 32; ++k4) {
            float4 pv[4], xv[4];
            #pragma unroll
            for (int cc = 0; cc < 4; ++cc) pv[cc] = pT4[k4 * 64 + cc * 16 + cg];
            #pragma unroll
            for (int r = 0; r < 4; ++r) xv[r] = xrow[r][k4];   // 16-lane broadcast
            #pragma unroll
            for (int r = 0; r < 4; ++r) {
                #pragma unroll
                for (int cc = 0; cc < 4; ++cc) {
                    float d;
                    d = xv[r].x - pv[cc].x; acc[r][cc] = fmaf(d, fabsf(d), acc[r][cc]);
                    d = xv[r].y - pv[cc].y; acc[r][cc] = fmaf(d, fabsf(d), acc[r][cc]);
                    d = xv[r].z - pv[cc].z; acc[r][cc] = fmaf(d, fabsf(d), acc[r][cc]);
                    d = xv[r].w - pv[cc].w; acc[r][cc] = fmaf(d, fabsf(d), acc[r][cc]);
                }
            }
        }

        const float ninv_d = -1.f / (float)D;
        float lsum = 0.f;
        #pragma unroll
        for (int r = 0; r < 4; ++r) {
            float dv0 = acc[r][0] * ninv_d, dv1 = acc[r][1] * ninv_d;
            float dv2 = acc[r][2] * ninv_d, dv3 = acc[r][3] * ninv_d;
            float mx = fmaxf(fmaxf(dv0, dv1), fmaxf(dv2, dv3));
            #pragma unroll
            for (int off = 8; off; off >>= 1) mx = fmaxf(mx, __shfl_xor(mx, off));
            float se = __expf(dv0 - mx) + __expf(dv1 - mx) +
                       __expf(dv2 - mx) + __expf(dv3 - mx);
            #pragma unroll
            for (int off = 8; off; off >>= 1) se += __shfl_xor(se, off);
            const float lse = mx + __logf(se);

            const int yt  = y[row0 + rbase + r];     // uniform within 16-lane group
            const int cct = yt & 3, cgt = yt >> 2;   // class c = 4*cg + cc
            const float v01 = (cct & 1) ? dv1 : dv0;
            const float v23 = (cct & 1) ? dv3 : dv2;
            const float val = (cct & 2) ? v23 : v01;
            const float dy  = __shfl(val, (lane & 48) | cgt);
            lsum += lse - dy;                        // -logp[y]
        }

        lsum += __shfl_xor(lsum, 16);                // sum 4 rg-groups
        lsum += __shfl_xor(lsum, 32);

        if (lane == 0) wsum[wid] = lsum;
        __syncthreads();
        if (tid == 0) {
            const float tot = (wsum[0] + wsum[1] + wsum[2] + wsum[3]) * (1.f / (float)M_HALF);
            atomicAdd(out, tot);
        }
    }
}

extern "C" void kernel_launch(void* const* d_in, const int* in_sizes, int n_in,
                              void* d_out, int out_size, void* d_ws, size_t ws_size,
                              hipStream_t stream) {
    const float* x = (const float*)d_in[0];   // [32768][128]
    const int*   y = (const int*)d_in[1];     // [32768]
    float* out = (float*)d_out;

    float* ws_f     = (float*)d_ws;
    int*   syncCnt  = (int*)ws_f;                        // 1 int (use 64f slot)
    float* pTg      = ws_f + 64;                         // 8192 floats
    float* partials = pTg + D * C;                       // 256*8192 = 8 MB

    hipMemsetAsync(syncCnt, 0, sizeof(int), stream);
    fused_proto_loss<<<NBLK, NTHR, 0, stream>>>(x, y, partials, pTg, syncCnt, out);
}